// Round 4
// baseline (612.964 us; speedup 1.0000x reference)
//
#include <hip/hip_runtime.h>
#include <hip/hip_bf16.h>
#include <cstdint>

typedef unsigned short u16;
typedef __bf16 bf16x8 __attribute__((ext_vector_type(8)));
typedef float f32x4 __attribute__((ext_vector_type(4)));

__device__ __forceinline__ u16 f2bf(float f) {
  unsigned int u = __float_as_uint(f);
  u += 0x7FFFu + ((u >> 16) & 1u);
  return (u16)(u >> 16);
}
__device__ __forceinline__ unsigned int pack2(float a, float b) {
  return (unsigned int)f2bf(a) | ((unsigned int)f2bf(b) << 16);
}

// ---------------- cast fp32 -> bf16 (vectorized) ----------------
__global__ __launch_bounds__(256) void cast_bf16_k(const float* __restrict__ in,
                                                   u16* __restrict__ out) {
  const int i = (blockIdx.x * 256 + threadIdx.x) * 4;
  const float4 v = *(const float4*)(in + i);
  uint2 p;
  p.x = pack2(v.x, v.y);
  p.y = pack2(v.z, v.w);
  *(uint2*)(out + i) = p;
}

// ---------------- transpose + cast: in[R][C] fp32 -> out[C][R] bf16 ----------------
__global__ __launch_bounds__(256) void transpose_cast_k(const float* __restrict__ in,
                                                        u16* __restrict__ out,
                                                        int R, int C) {
  __shared__ float tile[32][33];
  const int bx = blockIdx.x * 32, by = blockIdx.y * 32;
  const int tx = threadIdx.x & 31, ty = threadIdx.x >> 5;  // ty 0..7
#pragma unroll
  for (int i = 0; i < 32; i += 8)
    tile[ty + i][tx] = in[(size_t)(by + ty + i) * C + (bx + tx)];
  __syncthreads();
#pragma unroll
  for (int i = 0; i < 32; i += 8)
    out[(size_t)(bx + ty + i) * R + (by + tx)] = f2bf(tile[tx][ty + i]);
}

// ================ 256x256 8-phase GEMM (T2+T3+T4+T5) ================
// C[M,N] = A[M,K](bf16) @ Bt[N,K](bf16)^T + bias, epilogues as before.
// 8 waves (2M x 4N), per-wave output 128x64, BK=64, 128 KiB LDS dbuf.
// LDS layout: [buf0: A 32K | B 32K][buf1: A 32K | B 32K]; rows 128B,
// XOR-swizzled byte ^= ((row&7)<<4) via pre-swizzled global source.
// Schedule per K-tile t (4 phases):
//  q0: read A(t) rows mh0 + B(t) nh0 | stage Bh0(t+1) | sync | MFMA(0,0)
//  q1: read A(t) mh1                 | stage Bh1(t+1) | sync | MFMA(1,0)
//  q2: read B(t) nh1                 | stage Ah0(t+2) | sync | MFMA(0,1)
//  q3:                               | stage Ah1(t+2) | vmcnt(4) | MFMA(1,1)
// A slots dead after q1 barrier, B slots after q2 barrier -> stage targets safe.
// vmcnt(4) guarantees B(t+1) landed by (t,q3) and A(t+2) by (t+1,q3).
template <int EPI>
__global__ __launch_bounds__(512, 2) void gemm8(
    const u16* __restrict__ A, const u16* __restrict__ Bt,
    const float* __restrict__ bias, const float* __restrict__ resid,
    float* __restrict__ out_f, u16* __restrict__ out_b,
    u16* __restrict__ q_out, u16* __restrict__ k_out, u16* __restrict__ vt_out,
    int M, int N, int K) {
  __shared__ char lds[131072];
  const int tid = threadIdx.x;
  const int wave = tid >> 6, lane = tid & 63;
  const int llo = lane & 15, lhi = lane >> 4;
  const int wm = wave >> 2, wn = wave & 3;
  const int NT = K >> 6;
  const int nbx = N >> 8;
  // XCD-aware block swizzle (all grids are multiples of 8)
  const int cpx = gridDim.x >> 3;
  const int wg = (blockIdx.x & 7) * cpx + (blockIdx.x >> 3);
  const int m0 = (wg / nbx) << 8, n0 = (wg % nbx) << 8;

  // staging source geometry: thread stages dest row (c*64 + tid>>3), col (tid&7)*16
  const int rloc = tid >> 3;
  const int scol = (((tid & 7) * 16) ^ ((rloc & 7) << 4)) >> 1;  // elements
  const int swz = (llo & 7) << 4;

  f32x4 acc[8][4] = {};
  bf16x8 aF[2][4][2], bF[2][2][2];

#define STAGE_A(tt, hi)                                                         \
  if ((tt) < NT) {                                                              \
    char* db_ = lds + (((tt) & 1) << 16);                                       \
    _Pragma("unroll") for (int c_ = 0; c_ < 2; ++c_) {                          \
      const u16* g_ =                                                           \
          A + (size_t)(m0 + (hi) * 128 + c_ * 64 + rloc) * K + (tt) * 64 + scol;\
      __builtin_amdgcn_global_load_lds(                                         \
          (const __attribute__((address_space(1))) unsigned int*)g_,            \
          (__attribute__((address_space(3))) unsigned int*)(db_ + (hi) * 16384 +\
                                                           c_ * 8192 + wave * 1024), \
          16, 0, 0);                                                            \
    }                                                                           \
  }

#define STAGE_B(tt, hi)                                                         \
  if ((tt) < NT) {                                                              \
    char* db_ = lds + (((tt) & 1) << 16) + 32768;                               \
    _Pragma("unroll") for (int c_ = 0; c_ < 2; ++c_) {                          \
      const u16* g_ =                                                           \
          Bt + (size_t)(n0 + (hi) * 128 + c_ * 64 + rloc) * K + (tt) * 64 + scol;\
      __builtin_amdgcn_global_load_lds(                                         \
          (const __attribute__((address_space(1))) unsigned int*)g_,            \
          (__attribute__((address_space(3))) unsigned int*)(db_ + (hi) * 16384 +\
                                                           c_ * 8192 + wave * 1024), \
          16, 0, 0);                                                            \
    }                                                                           \
  }

#define LOAD_A(mh)                                                              \
  _Pragma("unroll") for (int mq_ = 0; mq_ < 4; ++mq_)                           \
  _Pragma("unroll") for (int kk_ = 0; kk_ < 2; ++kk_)                           \
    aF[mh][mq_][kk_] = *(const bf16x8*)(ldsA + (wm * 128 + (mh) * 64 + mq_ * 16 + llo) * 128 + \
                                        ((kk_ * 64 + lhi * 16) ^ swz));

#define LOAD_B(nh)                                                              \
  _Pragma("unroll") for (int nf_ = 0; nf_ < 2; ++nf_)                           \
  _Pragma("unroll") for (int kk_ = 0; kk_ < 2; ++kk_)                           \
    bF[nh][nf_][kk_] = *(const bf16x8*)(ldsB + (wn * 64 + (nh) * 32 + nf_ * 16 + llo) * 128 + \
                                        ((kk_ * 64 + lhi * 16) ^ swz));

#define DO_MFMA(mh, nh)                                                         \
  _Pragma("unroll") for (int mq_ = 0; mq_ < 4; ++mq_)                           \
  _Pragma("unroll") for (int nf_ = 0; nf_ < 2; ++nf_)                           \
  _Pragma("unroll") for (int kk_ = 0; kk_ < 2; ++kk_)                           \
    acc[(mh) * 4 + mq_][(nh) * 2 + nf_] = __builtin_amdgcn_mfma_f32_16x16x32_bf16( \
        aF[mh][mq_][kk_], bF[nh][nf_][kk_], acc[(mh) * 4 + mq_][(nh) * 2 + nf_], 0, 0, 0);

#define SYNC_PRE                                      \
  __builtin_amdgcn_s_barrier();                       \
  asm volatile("s_waitcnt lgkmcnt(0)" ::: "memory");  \
  __builtin_amdgcn_sched_barrier(0);                  \
  __builtin_amdgcn_s_setprio(1);

#define SYNC_POST                                     \
  __builtin_amdgcn_s_setprio(0);                      \
  __builtin_amdgcn_sched_barrier(0);                  \
  __builtin_amdgcn_s_barrier();

  // prologue: A(0), B(0), A(1) staged; wait A(0)+B(0) landed (4 loads in flight)
  STAGE_A(0, 0) STAGE_A(0, 1) STAGE_B(0, 0) STAGE_B(0, 1) STAGE_A(1, 0) STAGE_A(1, 1)
  asm volatile("s_waitcnt vmcnt(4)" ::: "memory");
  __builtin_amdgcn_s_barrier();

  for (int t = 0; t < NT; ++t) {
    const char* ldsA = lds + ((t & 1) << 16);
    const char* ldsB = ldsA + 32768;
    // q0
    LOAD_A(0) LOAD_B(0)
    STAGE_B(t + 1, 0)
    SYNC_PRE DO_MFMA(0, 0) SYNC_POST
    // q1
    LOAD_A(1)
    STAGE_B(t + 1, 1)
    SYNC_PRE DO_MFMA(1, 0) SYNC_POST
    // q2
    LOAD_B(1)
    STAGE_A(t + 2, 0)
    SYNC_PRE DO_MFMA(0, 1) SYNC_POST
    // q3
    STAGE_A(t + 2, 1)
    asm volatile("s_waitcnt vmcnt(4)" ::: "memory");
    SYNC_PRE DO_MFMA(1, 1) SYNC_POST
  }

  // epilogue
#pragma unroll
  for (int mf = 0; mf < 8; ++mf) {
#pragma unroll
    for (int nf = 0; nf < 4; ++nf) {
      const int col = n0 + wn * 64 + nf * 16 + llo;
      const int rowb = m0 + wm * 128 + mf * 16 + lhi * 4;
      const float bv = bias[col];
#pragma unroll
      for (int r = 0; r < 4; ++r) {
        const int row = rowb + r;
        const float v = acc[mf][nf][r] + bv;
        if (EPI == 0) {
          const int which = col >> 10, rem = col & 1023;
          const int h = rem >> 6, d = rem & 63;
          const int b = row >> 10, tq = row & 1023;
          const size_t bh = (size_t)(b * 16 + h);
          const u16 u = f2bf(v);
          if (which == 0)
            q_out[(bh * 1024 + tq) * 64 + d] = u;
          else if (which == 1)
            k_out[(bh * 1024 + tq) * 64 + d] = u;
          else
            vt_out[(bh * 64 + d) * 1024 + tq] = u;
        } else if (EPI == 1) {
          out_f[(size_t)row * N + col] = v + resid[(size_t)row * N + col];
        } else {
          const float gl = 0.5f * v * (1.0f + erff(v * 0.70710678118f));
          out_b[(size_t)row * N + col] = f2bf(gl);
        }
      }
    }
  }
#undef STAGE_A
#undef STAGE_B
#undef LOAD_A
#undef LOAD_B
#undef DO_MFMA
#undef SYNC_PRE
#undef SYNC_POST
}

// ---------------- flash attention: block = (bh, 64 q-rows), 4 waves x 16 q ----------------
__global__ __launch_bounds__(256) void attn_flash_k(const u16* __restrict__ Qb,
                                                    const u16* __restrict__ Kb,
                                                    const u16* __restrict__ Vt,
                                                    u16* __restrict__ ctx) {
  __shared__ char lds[8192 + 8192 + 4 * 2048];
  char* Ks = lds;
  char* Vs = lds + 8192;
  const int tid = threadIdx.x;
  const int wave = tid >> 6, lane = tid & 63;
  const int llo = lane & 15, lhi = lane >> 4;
  char* Ps = lds + 16384 + wave * 2048;  // per-wave P scratch [16 q][128B]
  const int bh = blockIdx.y;
  const int q0 = blockIdx.x * 64 + wave * 16;
  const size_t hq = (size_t)bh * 1024 * 64;
  const int swz = (llo & 7) << 4;

  // Q fragments for q = q0 + llo  (B-operand of swapped QK^T)
  const u16* qrow = Qb + hq + (size_t)(q0 + llo) * 64;
  const bf16x8 qf0 = *(const bf16x8*)(qrow + lhi * 8);
  const bf16x8 qf1 = *(const bf16x8*)(qrow + 32 + lhi * 8);

  f32x4 O[4] = {};
  float m = -3.0e38f, l = 0.f;
  const float C = 0.18033688011112042f;  // 0.125 * log2(e)

  for (int t = 0; t < 16; ++t) {
    const int kv0 = t * 64;
    __syncthreads();  // previous tile's LDS reads complete
#pragma unroll
    for (int j = 0; j < 2; ++j) {
      const int p = (j * 256 + tid) * 16;            // dest byte (linear)
      const int r = p >> 7;                          // LDS row 0..63
      const int c = (p & 127) ^ ((r & 7) << 4);      // pre-swizzled source col (bytes)
      const u16* gk = Kb + hq + (size_t)(kv0 + r) * 64 + (c >> 1);
      __builtin_amdgcn_global_load_lds(
          (const __attribute__((address_space(1))) unsigned int*)gk,
          (__attribute__((address_space(3))) unsigned int*)(Ks + (j * 256 + wave * 64) * 16),
          16, 0, 0);
      const u16* gv = Vt + (size_t)bh * 64 * 1024 + (size_t)r * 1024 + kv0 + (c >> 1);
      __builtin_amdgcn_global_load_lds(
          (const __attribute__((address_space(1))) unsigned int*)gv,
          (__attribute__((address_space(3))) unsigned int*)(Vs + (j * 256 + wave * 64) * 16),
          16, 0, 0);
    }
    __syncthreads();  // staged data visible

    // QK^T: S[k][q] tiles; lane holds q=llo, k = kt*16 + lhi*4 + r
    f32x4 s[4];
#pragma unroll
    for (int kt = 0; kt < 4; ++kt) {
      const int row = kt * 16 + llo;
      const bf16x8 k0 = *(const bf16x8*)(Ks + row * 128 + ((lhi * 16) ^ swz));
      const bf16x8 k1 = *(const bf16x8*)(Ks + row * 128 + ((64 + lhi * 16) ^ swz));
      f32x4 a = {};
      a = __builtin_amdgcn_mfma_f32_16x16x32_bf16(k0, qf0, a, 0, 0, 0);
      a = __builtin_amdgcn_mfma_f32_16x16x32_bf16(k1, qf1, a, 0, 0, 0);
      s[kt] = a;
    }

    // online softmax (raw scores; 1/8 folded into exp2 constant)
    float tmax = -3.0e38f;
#pragma unroll
    for (int kt = 0; kt < 4; ++kt)
#pragma unroll
      for (int r = 0; r < 4; ++r) tmax = fmaxf(tmax, s[kt][r]);
    tmax = fmaxf(tmax, __shfl_xor(tmax, 16));
    tmax = fmaxf(tmax, __shfl_xor(tmax, 32));
    const float mnew = fmaxf(m, tmax);
    const float sc = exp2f((m - mnew) * C);
    float tsum = 0.f;
#pragma unroll
    for (int kt = 0; kt < 4; ++kt)
#pragma unroll
      for (int r = 0; r < 4; ++r) {
        const float pv = exp2f((s[kt][r] - mnew) * C);
        s[kt][r] = pv;
        tsum += pv;
      }
    tsum += __shfl_xor(tsum, 16);
    tsum += __shfl_xor(tsum, 32);
    l = l * sc + tsum;
    m = mnew;
#pragma unroll
    for (int dt = 0; dt < 4; ++dt) O[dt] *= sc;

    // P (bf16) -> wave-local LDS, re-fragment k-quads into k-octets
#pragma unroll
    for (int kt = 0; kt < 4; ++kt) {
      uint2 pk;
      pk.x = pack2(s[kt][0], s[kt][1]);
      pk.y = pack2(s[kt][2], s[kt][3]);
      *(uint2*)(Ps + llo * 128 + ((kt * 32 + lhi * 8) ^ swz)) = pk;
    }
    bf16x8 pb[2];
#pragma unroll
    for (int kc = 0; kc < 2; ++kc)
      pb[kc] = *(const bf16x8*)(Ps + llo * 128 + ((kc * 64 + lhi * 16) ^ swz));

    // O^T += V^T P^T : lane holds q=llo, d = dt*16 + lhi*4 + r
#pragma unroll
    for (int dt = 0; dt < 4; ++dt) {
      const int vrow = dt * 16 + llo;
#pragma unroll
      for (int kc = 0; kc < 2; ++kc) {
        const bf16x8 vf = *(const bf16x8*)(Vs + vrow * 128 + ((kc * 64 + lhi * 16) ^ swz));
        O[dt] = __builtin_amdgcn_mfma_f32_16x16x32_bf16(vf, pb[kc], O[dt], 0, 0, 0);
      }
    }
  }

  const float inv = 1.0f / l;
  const int b = bh >> 4, h = bh & 15;
  u16* crow = ctx + ((size_t)(b * 1024 + q0 + llo)) * 1024 + h * 64;
#pragma unroll
  for (int dt = 0; dt < 4; ++dt) {
    uint2 pk;
    pk.x = pack2(O[dt][0] * inv, O[dt][1] * inv);
    pk.y = pack2(O[dt][2] * inv, O[dt][3] * inv);
    *(uint2*)(crow + dt * 16 + lhi * 4) = pk;
  }
}

// ---------------- LayerNorm over D=1024; writes bf16 and/or fp32 ----------------
__global__ __launch_bounds__(256) void layernorm_k(const float* __restrict__ y,
                                                   const float* __restrict__ g,
                                                   const float* __restrict__ be,
                                                   u16* __restrict__ out_b,
                                                   float* __restrict__ out_f) {
  const int row = blockIdx.x;
  const int t = threadIdx.x;
  const float* yr = y + (size_t)row * 1024;
  const float4 v = *(const float4*)(yr + t * 4);
  float s = v.x + v.y + v.z + v.w;
  float s2 = v.x * v.x + v.y * v.y + v.z * v.z + v.w * v.w;
#pragma unroll
  for (int m = 1; m < 64; m <<= 1) {
    s += __shfl_xor(s, m);
    s2 += __shfl_xor(s2, m);
  }
  __shared__ float red[8];
  const int wv = t >> 6, lane = t & 63;
  if (lane == 0) {
    red[wv * 2] = s;
    red[wv * 2 + 1] = s2;
  }
  __syncthreads();
  s = red[0] + red[2] + red[4] + red[6];
  s2 = red[1] + red[3] + red[5] + red[7];
  const float mu = s * (1.0f / 1024.0f);
  const float var = s2 * (1.0f / 1024.0f) - mu * mu;
  const float inv = rsqrtf(var + 1e-5f);
  const int c = t * 4;
  const float4 gg = *(const float4*)(g + c);
  const float4 bb = *(const float4*)(be + c);
  const float o0 = (v.x - mu) * inv * gg.x + bb.x;
  const float o1 = (v.y - mu) * inv * gg.y + bb.y;
  const float o2 = (v.z - mu) * inv * gg.z + bb.z;
  const float o3 = (v.w - mu) * inv * gg.w + bb.w;
  if (out_f) {
    float4 o = {o0, o1, o2, o3};
    *(float4*)(out_f + (size_t)row * 1024 + c) = o;
  }
  if (out_b) {
    uint2 p;
    p.x = pack2(o0, o1);
    p.y = pack2(o2, o3);
    *(uint2*)(out_b + (size_t)row * 1024 + c) = p;
  }
}

// ---------------- launch ----------------
extern "C" void kernel_launch(void* const* d_in, const int* in_sizes, int n_in,
                              void* d_out, int out_size, void* d_ws, size_t ws_size,
                              hipStream_t stream) {
  const float* X = (const float*)d_in[0];
  const float* W_qkv = (const float*)d_in[1];
  const float* b_qkv = (const float*)d_in[2];
  const float* W_out = (const float*)d_in[3];
  const float* b_out = (const float*)d_in[4];
  const float* ln1_g = (const float*)d_in[5];
  const float* ln1_b = (const float*)d_in[6];
  const float* ln2_g = (const float*)d_in[7];
  const float* ln2_b = (const float*)d_in[8];
  const float* W_ff1 = (const float*)d_in[9];
  const float* b_ff1 = (const float*)d_in[10];
  const float* W_ff2 = (const float*)d_in[11];
  const float* b_ff2 = (const float*)d_in[12];

  char* ws = (char*)d_ws;
  size_t off = 0;
  auto alloc = [&](size_t bytes) {
    char* p = ws + off;
    off += (bytes + 255) & ~(size_t)255;
    return p;
  };
  u16* Xb = (u16*)alloc(8192ull * 1024 * 2);       // X bf16
  u16* Wqkvt = (u16*)alloc(3072ull * 1024 * 2);    // W_qkv^T bf16
  u16* Woutt = (u16*)alloc(1024ull * 1024 * 2);    // W_out^T bf16
  u16* Wff1t = (u16*)alloc(4096ull * 1024 * 2);    // W_ff1^T bf16
  u16* Wff2t = (u16*)alloc(1024ull * 4096 * 2);    // W_ff2^T bf16
  u16* Qb = (u16*)alloc(128ull * 1024 * 64 * 2);   // Q [bh][t][d]
  u16* Kb = (u16*)alloc(128ull * 1024 * 64 * 2);   // K [bh][t][d]
  u16* Vtb = (u16*)alloc(128ull * 1024 * 64 * 2);  // V^T [bh][d][t]
  u16* ctx = (u16*)alloc(8192ull * 1024 * 2);      // attention context bf16
  float* y1 = (float*)alloc(8192ull * 1024 * 4);   // pre-LN1 residual sum; reused as y2
  u16* X1b = (u16*)alloc(8192ull * 1024 * 2);      // LN1 out bf16
  float* X1f = (float*)alloc(8192ull * 1024 * 4);  // LN1 out fp32
  u16* hbuf = Qb;  // FF1 output (64 MB) aliases Qb..ctx (dead after out-proj)

  cast_bf16_k<<<8192, 256, 0, stream>>>(X, Xb);
  transpose_cast_k<<<dim3(96, 32), 256, 0, stream>>>(W_qkv, Wqkvt, 1024, 3072);
  transpose_cast_k<<<dim3(32, 32), 256, 0, stream>>>(W_out, Woutt, 1024, 1024);
  transpose_cast_k<<<dim3(128, 32), 256, 0, stream>>>(W_ff1, Wff1t, 1024, 4096);
  transpose_cast_k<<<dim3(32, 128), 256, 0, stream>>>(W_ff2, Wff2t, 4096, 1024);

  // QKV projection + head scatter   (grid 384 = 32m x 12n)
  gemm8<0><<<384, 512, 0, stream>>>(Xb, Wqkvt, b_qkv, nullptr, nullptr, nullptr,
                                    Qb, Kb, Vtb, 8192, 3072, 1024);
  // flash attention
  attn_flash_k<<<dim3(16, 128), 256, 0, stream>>>(Qb, Kb, Vtb, ctx);
  // out projection + bias + residual(X) -> y1 fp32   (grid 128)
  gemm8<1><<<128, 512, 0, stream>>>(ctx, Woutt, b_out, X, y1, nullptr,
                                    nullptr, nullptr, nullptr, 8192, 1024, 1024);
  // LN1 -> X1 (bf16 + fp32)
  layernorm_k<<<8192, 256, 0, stream>>>(y1, ln1_g, ln1_b, X1b, X1f);
  // FF1 + bias + exact GELU -> h bf16   (grid 512)
  gemm8<2><<<512, 512, 0, stream>>>(X1b, Wff1t, b_ff1, nullptr, nullptr, hbuf,
                                    nullptr, nullptr, nullptr, 8192, 4096, 1024);
  // FF2 + bias + residual(X1) -> y2 fp32   (grid 128)
  gemm8<1><<<128, 512, 0, stream>>>(hbuf, Wff2t, b_ff2, X1f, y1, nullptr,
                                    nullptr, nullptr, nullptr, 8192, 1024, 4096);
  // LN2 -> output fp32
  layernorm_k<<<8192, 256, 0, stream>>>(y1, ln2_g, ln2_b, nullptr, (float*)d_out);
}

// Round 5
// 532.000 us; speedup vs baseline: 1.1522x; 1.1522x over previous
//
#include <hip/hip_runtime.h>
#include <hip/hip_bf16.h>
#include <cstdint>

typedef unsigned short u16;
typedef __bf16 bf16x8 __attribute__((ext_vector_type(8)));
typedef float f32x4 __attribute__((ext_vector_type(4)));

__device__ __forceinline__ u16 f2bf(float f) {
  unsigned int u = __float_as_uint(f);
  u += 0x7FFFu + ((u >> 16) & 1u);
  return (u16)(u >> 16);
}
__device__ __forceinline__ unsigned int pack2(float a, float b) {
  return (unsigned int)f2bf(a) | ((unsigned int)f2bf(b) << 16);
}

// ---------------- cast fp32 -> bf16 (vectorized) ----------------
__global__ __launch_bounds__(256) void cast_bf16_k(const float* __restrict__ in,
                                                   u16* __restrict__ out) {
  const int i = (blockIdx.x * 256 + threadIdx.x) * 4;
  const float4 v = *(const float4*)(in + i);
  uint2 p;
  p.x = pack2(v.x, v.y);
  p.y = pack2(v.z, v.w);
  *(uint2*)(out + i) = p;
}

// ---------------- transpose + cast: in[R][C] fp32 -> out[C][R] bf16 ----------------
__global__ __launch_bounds__(256) void transpose_cast_k(const float* __restrict__ in,
                                                        u16* __restrict__ out,
                                                        int R, int C) {
  __shared__ float tile[32][33];
  const int bx = blockIdx.x * 32, by = blockIdx.y * 32;
  const int tx = threadIdx.x & 31, ty = threadIdx.x >> 5;  // ty 0..7
#pragma unroll
  for (int i = 0; i < 32; i += 8)
    tile[ty + i][tx] = in[(size_t)(by + ty + i) * C + (bx + tx)];
  __syncthreads();
#pragma unroll
  for (int i = 0; i < 32; i += 8)
    out[(size_t)(bx + ty + i) * R + (by + tx)] = f2bf(tile[tx][ty + i]);
}

// ---------------- shared epilogue ----------------
template <int EPI>
__device__ __forceinline__ void epi_store(float v, int row, int col, int N,
                                          const float* __restrict__ resid,
                                          float* __restrict__ out_f,
                                          u16* __restrict__ out_b,
                                          u16* __restrict__ q_out,
                                          u16* __restrict__ k_out,
                                          u16* __restrict__ vt_out) {
  if (EPI == 0) {
    const int which = col >> 10, rem = col & 1023;
    const int h = rem >> 6, d = rem & 63;
    const int b = row >> 10, tq = row & 1023;
    const size_t bh = (size_t)(b * 16 + h);
    const u16 u = f2bf(v);
    if (which == 0)
      q_out[(bh * 1024 + tq) * 64 + d] = u;
    else if (which == 1)
      k_out[(bh * 1024 + tq) * 64 + d] = u;
    else
      vt_out[(bh * 64 + d) * 1024 + tq] = u;
  } else if (EPI == 1) {
    out_f[(size_t)row * N + col] = v + resid[(size_t)row * N + col];
  } else {
    const float gl = 0.5f * v * (1.0f + erff(v * 0.70710678118f));
    out_b[(size_t)row * N + col] = f2bf(gl);
  }
}

#define SYNC_PRE                                      \
  __builtin_amdgcn_s_barrier();                       \
  asm volatile("s_waitcnt lgkmcnt(0)" ::: "memory");  \
  __builtin_amdgcn_sched_barrier(0);                  \
  __builtin_amdgcn_s_setprio(1);

#define SYNC_POST                                     \
  __builtin_amdgcn_s_setprio(0);                      \
  __builtin_amdgcn_sched_barrier(0);                  \
  __builtin_amdgcn_s_barrier();

// ================ 256x256 8-phase GEMM (T2+T3+T4+T5) ================
// 8 waves (2M x 4N), per-wave output 128x64, BK=64, 128 KiB LDS dbuf.
// Schedule per K-tile t (4 phases): see R2 notes; vmcnt(4) only at q3.
template <int EPI>
__global__ __launch_bounds__(512, 2) void gemm8(
    const u16* __restrict__ A, const u16* __restrict__ Bt,
    const float* __restrict__ bias, const float* __restrict__ resid,
    float* __restrict__ out_f, u16* __restrict__ out_b,
    u16* __restrict__ q_out, u16* __restrict__ k_out, u16* __restrict__ vt_out,
    int M, int N, int K) {
  __shared__ char lds[131072];
  const int tid = threadIdx.x;
  const int wave = tid >> 6, lane = tid & 63;
  const int llo = lane & 15, lhi = lane >> 4;
  const int wm = wave >> 2, wn = wave & 3;
  const int NT = K >> 6;
  const int nbx = N >> 8;
  const int cpx = gridDim.x >> 3;
  const int wg = (blockIdx.x & 7) * cpx + (blockIdx.x >> 3);
  const int m0 = (wg / nbx) << 8, n0 = (wg % nbx) << 8;

  const int rloc = tid >> 3;
  const int scol = (((tid & 7) * 16) ^ ((rloc & 7) << 4)) >> 1;  // elements
  const int swz = (llo & 7) << 4;

  f32x4 acc[8][4] = {};
  bf16x8 aF[2][4][2], bF[2][2][2];

#define STAGE_A(tt, hi)                                                         \
  if ((tt) < NT) {                                                              \
    char* db_ = lds + (((tt) & 1) << 16);                                       \
    _Pragma("unroll") for (int c_ = 0; c_ < 2; ++c_) {                          \
      const u16* g_ =                                                           \
          A + (size_t)(m0 + (hi) * 128 + c_ * 64 + rloc) * K + (tt) * 64 + scol;\
      __builtin_amdgcn_global_load_lds(                                         \
          (const __attribute__((address_space(1))) unsigned int*)g_,            \
          (__attribute__((address_space(3))) unsigned int*)(db_ + (hi) * 16384 +\
                                                           c_ * 8192 + wave * 1024), \
          16, 0, 0);                                                            \
    }                                                                           \
  }

#define STAGE_B(tt, hi)                                                         \
  if ((tt) < NT) {                                                              \
    char* db_ = lds + (((tt) & 1) << 16) + 32768;                               \
    _Pragma("unroll") for (int c_ = 0; c_ < 2; ++c_) {                          \
      const u16* g_ =                                                           \
          Bt + (size_t)(n0 + (hi) * 128 + c_ * 64 + rloc) * K + (tt) * 64 + scol;\
      __builtin_amdgcn_global_load_lds(                                         \
          (const __attribute__((address_space(1))) unsigned int*)g_,            \
          (__attribute__((address_space(3))) unsigned int*)(db_ + (hi) * 16384 +\
                                                           c_ * 8192 + wave * 1024), \
          16, 0, 0);                                                            \
    }                                                                           \
  }

#define LOAD_A(mh)                                                              \
  _Pragma("unroll") for (int mq_ = 0; mq_ < 4; ++mq_)                           \
  _Pragma("unroll") for (int kk_ = 0; kk_ < 2; ++kk_)                           \
    aF[mh][mq_][kk_] = *(const bf16x8*)(ldsA + (wm * 128 + (mh) * 64 + mq_ * 16 + llo) * 128 + \
                                        ((kk_ * 64 + lhi * 16) ^ swz));

#define LOAD_B(nh)                                                              \
  _Pragma("unroll") for (int nf_ = 0; nf_ < 2; ++nf_)                           \
  _Pragma("unroll") for (int kk_ = 0; kk_ < 2; ++kk_)                           \
    bF[nh][nf_][kk_] = *(const bf16x8*)(ldsB + (wn * 64 + (nh) * 32 + nf_ * 16 + llo) * 128 + \
                                        ((kk_ * 64 + lhi * 16) ^ swz));

#define DO_MFMA(mh, nh)                                                         \
  _Pragma("unroll") for (int mq_ = 0; mq_ < 4; ++mq_)                           \
  _Pragma("unroll") for (int nf_ = 0; nf_ < 2; ++nf_)                           \
  _Pragma("unroll") for (int kk_ = 0; kk_ < 2; ++kk_)                           \
    acc[(mh) * 4 + mq_][(nh) * 2 + nf_] = __builtin_amdgcn_mfma_f32_16x16x32_bf16( \
        aF[mh][mq_][kk_], bF[nh][nf_][kk_], acc[(mh) * 4 + mq_][(nh) * 2 + nf_], 0, 0, 0);

  STAGE_A(0, 0) STAGE_A(0, 1) STAGE_B(0, 0) STAGE_B(0, 1) STAGE_A(1, 0) STAGE_A(1, 1)
  asm volatile("s_waitcnt vmcnt(4)" ::: "memory");
  __builtin_amdgcn_s_barrier();

  for (int t = 0; t < NT; ++t) {
    const char* ldsA = lds + ((t & 1) << 16);
    const char* ldsB = ldsA + 32768;
    LOAD_A(0) LOAD_B(0)
    STAGE_B(t + 1, 0)
    SYNC_PRE DO_MFMA(0, 0) SYNC_POST
    LOAD_A(1)
    STAGE_B(t + 1, 1)
    SYNC_PRE DO_MFMA(1, 0) SYNC_POST
    LOAD_B(1)
    STAGE_A(t + 2, 0)
    SYNC_PRE DO_MFMA(0, 1) SYNC_POST
    STAGE_A(t + 2, 1)
    asm volatile("s_waitcnt vmcnt(4)" ::: "memory");
    SYNC_PRE DO_MFMA(1, 1) SYNC_POST
  }

#pragma unroll
  for (int mf = 0; mf < 8; ++mf) {
#pragma unroll
    for (int nf = 0; nf < 4; ++nf) {
      const int col = n0 + wn * 64 + nf * 16 + llo;
      const int rowb = m0 + wm * 128 + mf * 16 + lhi * 4;
      const float bv = bias[col];
#pragma unroll
      for (int r = 0; r < 4; ++r)
        epi_store<EPI>(acc[mf][nf][r] + bv, rowb + r, col, N, resid, out_f, out_b,
                       q_out, k_out, vt_out);
    }
  }
#undef STAGE_A
#undef STAGE_B
#undef LOAD_A
#undef LOAD_B
#undef DO_MFMA
}

// ================ 256x128 8-phase GEMM (same schedule, BN=128) ================
// 8 waves (4M x 2N), per-wave output 64x64, BK=64, 96 KiB LDS dbuf.
// Per K-tile t: q0: rd A0+B0 | stage B(t+1)   | sync | MFMA(0,0)
//               q1: rd A1    | stage A(t+2,0) | sync | MFMA(1,0)
//               q2: rd B1    | stage A(t+2,1) | sync | MFMA(0,1)
//               q3:          | vmcnt(4)       | sync | MFMA(1,1)
// A(t+2) overwrites current buf's A half only after its reads drained (q0/q1
// barriers). vmcnt(4) keeps only A(t+2)'s 4 loads in flight -> B(t+1), A(t+1) landed.
template <int EPI>
__global__ __launch_bounds__(512, 2) void gemm8n(
    const u16* __restrict__ A, const u16* __restrict__ Bt,
    const float* __restrict__ bias, const float* __restrict__ resid,
    float* __restrict__ out_f, u16* __restrict__ out_b,
    u16* __restrict__ q_out, u16* __restrict__ k_out, u16* __restrict__ vt_out,
    int M, int N, int K) {
  __shared__ char lds[98304];
  const int tid = threadIdx.x;
  const int wave = tid >> 6, lane = tid & 63;
  const int llo = lane & 15, lhi = lane >> 4;
  const int wm = wave >> 1, wn = wave & 1;
  const int NT = K >> 6;
  const int nbx = N >> 7;
  const int cpx = gridDim.x >> 3;
  const int wg = (blockIdx.x & 7) * cpx + (blockIdx.x >> 3);
  const int m0 = (wg / nbx) << 8, n0 = (wg % nbx) << 7;

  const int rloc = tid >> 3;
  const int scol = (((tid & 7) * 16) ^ ((rloc & 7) << 4)) >> 1;  // elements
  const int swz = (llo & 7) << 4;

  f32x4 acc[4][4] = {};
  bf16x8 aF[2][2][2], bF[2][2][2];

#define STAGE_A(tt, hi)                                                         \
  if ((tt) < NT) {                                                              \
    char* db_ = lds + ((tt) & 1) * 49152;                                       \
    _Pragma("unroll") for (int c_ = 0; c_ < 2; ++c_) {                          \
      const u16* g_ =                                                           \
          A + (size_t)(m0 + (hi) * 128 + c_ * 64 + rloc) * K + (tt) * 64 + scol;\
      __builtin_amdgcn_global_load_lds(                                         \
          (const __attribute__((address_space(1))) unsigned int*)g_,            \
          (__attribute__((address_space(3))) unsigned int*)(db_ + (hi) * 16384 +\
                                                           c_ * 8192 + wave * 1024), \
          16, 0, 0);                                                            \
    }                                                                           \
  }

#define STAGE_B(tt)                                                             \
  if ((tt) < NT) {                                                              \
    char* db_ = lds + ((tt) & 1) * 49152 + 32768;                               \
    _Pragma("unroll") for (int c_ = 0; c_ < 2; ++c_) {                          \
      const u16* g_ =                                                           \
          Bt + (size_t)(n0 + c_ * 64 + rloc) * K + (tt) * 64 + scol;            \
      __builtin_amdgcn_global_load_lds(                                         \
          (const __attribute__((address_space(1))) unsigned int*)g_,            \
          (__attribute__((address_space(3))) unsigned int*)(db_ +               \
                                                           c_ * 8192 + wave * 1024), \
          16, 0, 0);                                                            \
    }                                                                           \
  }

#define LOAD_A(mh)                                                              \
  _Pragma("unroll") for (int mf_ = 0; mf_ < 2; ++mf_)                           \
  _Pragma("unroll") for (int kk_ = 0; kk_ < 2; ++kk_)                           \
    aF[mh][mf_][kk_] = *(const bf16x8*)(ldsA + (wm * 64 + (mh) * 32 + mf_ * 16 + llo) * 128 + \
                                        ((kk_ * 64 + lhi * 16) ^ swz));

#define LOAD_B(nh)                                                              \
  _Pragma("unroll") for (int nf_ = 0; nf_ < 2; ++nf_)                           \
  _Pragma("unroll") for (int kk_ = 0; kk_ < 2; ++kk_)                           \
    bF[nh][nf_][kk_] = *(const bf16x8*)(ldsB + (wn * 64 + (nh) * 32 + nf_ * 16 + llo) * 128 + \
                                        ((kk_ * 64 + lhi * 16) ^ swz));

#define DO_MFMA(mh, nh)                                                         \
  _Pragma("unroll") for (int mf_ = 0; mf_ < 2; ++mf_)                           \
  _Pragma("unroll") for (int nf_ = 0; nf_ < 2; ++nf_)                           \
  _Pragma("unroll") for (int kk_ = 0; kk_ < 2; ++kk_)                           \
    acc[(mh) * 2 + mf_][(nh) * 2 + nf_] = __builtin_amdgcn_mfma_f32_16x16x32_bf16( \
        aF[mh][mf_][kk_], bF[nh][nf_][kk_], acc[(mh) * 2 + mf_][(nh) * 2 + nf_], 0, 0, 0);

  STAGE_A(0, 0) STAGE_A(0, 1) STAGE_B(0) STAGE_A(1, 0) STAGE_A(1, 1)
  asm volatile("s_waitcnt vmcnt(4)" ::: "memory");
  __builtin_amdgcn_s_barrier();

  for (int t = 0; t < NT; ++t) {
    const char* ldsA = lds + (t & 1) * 49152;
    const char* ldsB = ldsA + 32768;
    LOAD_A(0) LOAD_B(0)
    STAGE_B(t + 1)
    SYNC_PRE DO_MFMA(0, 0) SYNC_POST
    LOAD_A(1)
    STAGE_A(t + 2, 0)
    SYNC_PRE DO_MFMA(1, 0) SYNC_POST
    LOAD_B(1)
    STAGE_A(t + 2, 1)
    SYNC_PRE DO_MFMA(0, 1) SYNC_POST
    asm volatile("s_waitcnt vmcnt(4)" ::: "memory");
    SYNC_PRE DO_MFMA(1, 1) SYNC_POST
  }

#pragma unroll
  for (int mf = 0; mf < 4; ++mf) {
#pragma unroll
    for (int nf = 0; nf < 4; ++nf) {
      const int col = n0 + wn * 64 + nf * 16 + llo;
      const int rowb = m0 + wm * 64 + mf * 16 + lhi * 4;
      const float bv = bias[col];
#pragma unroll
      for (int r = 0; r < 4; ++r)
        epi_store<EPI>(acc[mf][nf][r] + bv, rowb + r, col, N, resid, out_f, out_b,
                       q_out, k_out, vt_out);
    }
  }
#undef STAGE_A
#undef STAGE_B
#undef LOAD_A
#undef LOAD_B
#undef DO_MFMA
}

// ---------------- flash attention: block = (bh, 64 q-rows), 4 waves x 16 q ----------------
__global__ __launch_bounds__(256) void attn_flash_k(const u16* __restrict__ Qb,
                                                    const u16* __restrict__ Kb,
                                                    const u16* __restrict__ Vt,
                                                    u16* __restrict__ ctx) {
  __shared__ char lds[8192 + 8192 + 4 * 2048];
  char* Ks = lds;
  char* Vs = lds + 8192;
  const int tid = threadIdx.x;
  const int wave = tid >> 6, lane = tid & 63;
  const int llo = lane & 15, lhi = lane >> 4;
  char* Ps = lds + 16384 + wave * 2048;  // per-wave P scratch [16 q][128B]
  const int bh = blockIdx.y;
  const int q0 = blockIdx.x * 64 + wave * 16;
  const size_t hq = (size_t)bh * 1024 * 64;
  const int swz = (llo & 7) << 4;

  const u16* qrow = Qb + hq + (size_t)(q0 + llo) * 64;
  const bf16x8 qf0 = *(const bf16x8*)(qrow + lhi * 8);
  const bf16x8 qf1 = *(const bf16x8*)(qrow + 32 + lhi * 8);

  f32x4 O[4] = {};
  float m = -3.0e38f, l = 0.f;
  const float C = 0.18033688011112042f;  // 0.125 * log2(e)

  for (int t = 0; t < 16; ++t) {
    const int kv0 = t * 64;
    __syncthreads();
#pragma unroll
    for (int j = 0; j < 2; ++j) {
      const int p = (j * 256 + tid) * 16;
      const int r = p >> 7;
      const int c = (p & 127) ^ ((r & 7) << 4);
      const u16* gk = Kb + hq + (size_t)(kv0 + r) * 64 + (c >> 1);
      __builtin_amdgcn_global_load_lds(
          (const __attribute__((address_space(1))) unsigned int*)gk,
          (__attribute__((address_space(3))) unsigned int*)(Ks + (j * 256 + wave * 64) * 16),
          16, 0, 0);
      const u16* gv = Vt + (size_t)bh * 64 * 1024 + (size_t)r * 1024 + kv0 + (c >> 1);
      __builtin_amdgcn_global_load_lds(
          (const __attribute__((address_space(1))) unsigned int*)gv,
          (__attribute__((address_space(3))) unsigned int*)(Vs + (j * 256 + wave * 64) * 16),
          16, 0, 0);
    }
    __syncthreads();

    f32x4 s[4];
#pragma unroll
    for (int kt = 0; kt < 4; ++kt) {
      const int row = kt * 16 + llo;
      const bf16x8 k0 = *(const bf16x8*)(Ks + row * 128 + ((lhi * 16) ^ swz));
      const bf16x8 k1 = *(const bf16x8*)(Ks + row * 128 + ((64 + lhi * 16) ^ swz));
      f32x4 a = {};
      a = __builtin_amdgcn_mfma_f32_16x16x32_bf16(k0, qf0, a, 0, 0, 0);
      a = __builtin_amdgcn_mfma_f32_16x16x32_bf16(k1, qf1, a, 0, 0, 0);
      s[kt] = a;
    }

    float tmax = -3.0e38f;
#pragma unroll
    for (int kt = 0; kt < 4; ++kt)
#pragma unroll
      for (int r = 0; r < 4; ++r) tmax = fmaxf(tmax, s[kt][r]);
    tmax = fmaxf(tmax, __shfl_xor(tmax, 16));
    tmax = fmaxf(tmax, __shfl_xor(tmax, 32));
    const float mnew = fmaxf(m, tmax);
    const float sc = exp2f((m - mnew) * C);
    float tsum = 0.f;
#pragma unroll
    for (int kt = 0; kt < 4; ++kt)
#pragma unroll
      for (int r = 0; r < 4; ++r) {
        const float pv = exp2f((s[kt][r] - mnew) * C);
        s[kt][r] = pv;
        tsum += pv;
      }
    tsum += __shfl_xor(tsum, 16);
    tsum += __shfl_xor(tsum, 32);
    l = l * sc + tsum;
    m = mnew;
#pragma unroll
    for (int dt = 0; dt < 4; ++dt) O[dt] *= sc;

#pragma unroll
    for (int kt = 0; kt < 4; ++kt) {
      uint2 pk;
      pk.x = pack2(s[kt][0], s[kt][1]);
      pk.y = pack2(s[kt][2], s[kt][3]);
      *(uint2*)(Ps + llo * 128 + ((kt * 32 + lhi * 8) ^ swz)) = pk;
    }
    bf16x8 pb[2];
#pragma unroll
    for (int kc = 0; kc < 2; ++kc)
      pb[kc] = *(const bf16x8*)(Ps + llo * 128 + ((kc * 64 + lhi * 16) ^ swz));

#pragma unroll
    for (int dt = 0; dt < 4; ++dt) {
      const int vrow = dt * 16 + llo;
#pragma unroll
      for (int kc = 0; kc < 2; ++kc) {
        const bf16x8 vf = *(const bf16x8*)(Vs + vrow * 128 + ((kc * 64 + lhi * 16) ^ swz));
        O[dt] = __builtin_amdgcn_mfma_f32_16x16x32_bf16(vf, pb[kc], O[dt], 0, 0, 0);
      }
    }
  }

  const float inv = 1.0f / l;
  const int b = bh >> 4, h = bh & 15;
  u16* crow = ctx + ((size_t)(b * 1024 + q0 + llo)) * 1024 + h * 64;
#pragma unroll
  for (int dt = 0; dt < 4; ++dt) {
    uint2 pk;
    pk.x = pack2(O[dt][0] * inv, O[dt][1] * inv);
    pk.y = pack2(O[dt][2] * inv, O[dt][3] * inv);
    *(uint2*)(crow + dt * 16 + lhi * 4) = pk;
  }
}

// ---------------- LayerNorm over D=1024; writes bf16 and/or fp32 ----------------
__global__ __launch_bounds__(256) void layernorm_k(const float* __restrict__ y,
                                                   const float* __restrict__ g,
                                                   const float* __restrict__ be,
                                                   u16* __restrict__ out_b,
                                                   float* __restrict__ out_f) {
  const int row = blockIdx.x;
  const int t = threadIdx.x;
  const float* yr = y + (size_t)row * 1024;
  const float4 v = *(const float4*)(yr + t * 4);
  float s = v.x + v.y + v.z + v.w;
  float s2 = v.x * v.x + v.y * v.y + v.z * v.z + v.w * v.w;
#pragma unroll
  for (int m = 1; m < 64; m <<= 1) {
    s += __shfl_xor(s, m);
    s2 += __shfl_xor(s2, m);
  }
  __shared__ float red[8];
  const int wv = t >> 6, lane = t & 63;
  if (lane == 0) {
    red[wv * 2] = s;
    red[wv * 2 + 1] = s2;
  }
  __syncthreads();
  s = red[0] + red[2] + red[4] + red[6];
  s2 = red[1] + red[3] + red[5] + red[7];
  const float mu = s * (1.0f / 1024.0f);
  const float var = s2 * (1.0f / 1024.0f) - mu * mu;
  const float inv = rsqrtf(var + 1e-5f);
  const int c = t * 4;
  const float4 gg = *(const float4*)(g + c);
  const float4 bb = *(const float4*)(be + c);
  const float o0 = (v.x - mu) * inv * gg.x + bb.x;
  const float o1 = (v.y - mu) * inv * gg.y + bb.y;
  const float o2 = (v.z - mu) * inv * gg.z + bb.z;
  const float o3 = (v.w - mu) * inv * gg.w + bb.w;
  if (out_f) {
    float4 o = {o0, o1, o2, o3};
    *(float4*)(out_f + (size_t)row * 1024 + c) = o;
  }
  if (out_b) {
    uint2 p;
    p.x = pack2(o0, o1);
    p.y = pack2(o2, o3);
    *(uint2*)(out_b + (size_t)row * 1024 + c) = p;
  }
}

// ---------------- launch ----------------
extern "C" void kernel_launch(void* const* d_in, const int* in_sizes, int n_in,
                              void* d_out, int out_size, void* d_ws, size_t ws_size,
                              hipStream_t stream) {
  const float* X = (const float*)d_in[0];
  const float* W_qkv = (const float*)d_in[1];
  const float* b_qkv = (const float*)d_in[2];
  const float* W_out = (const float*)d_in[3];
  const float* b_out = (const float*)d_in[4];
  const float* ln1_g = (const float*)d_in[5];
  const float* ln1_b = (const float*)d_in[6];
  const float* ln2_g = (const float*)d_in[7];
  const float* ln2_b = (const float*)d_in[8];
  const float* W_ff1 = (const float*)d_in[9];
  const float* b_ff1 = (const float*)d_in[10];
  const float* W_ff2 = (const float*)d_in[11];
  const float* b_ff2 = (const float*)d_in[12];

  char* ws = (char*)d_ws;
  size_t off = 0;
  auto alloc = [&](size_t bytes) {
    char* p = ws + off;
    off += (bytes + 255) & ~(size_t)255;
    return p;
  };
  u16* Xb = (u16*)alloc(8192ull * 1024 * 2);       // X bf16
  u16* Wqkvt = (u16*)alloc(3072ull * 1024 * 2);    // W_qkv^T bf16
  u16* Woutt = (u16*)alloc(1024ull * 1024 * 2);    // W_out^T bf16
  u16* Wff1t = (u16*)alloc(4096ull * 1024 * 2);    // W_ff1^T bf16
  u16* Wff2t = (u16*)alloc(1024ull * 4096 * 2);    // W_ff2^T bf16
  u16* Qb = (u16*)alloc(128ull * 1024 * 64 * 2);   // Q [bh][t][d]
  u16* Kb = (u16*)alloc(128ull * 1024 * 64 * 2);   // K [bh][t][d]
  u16* Vtb = (u16*)alloc(128ull * 1024 * 64 * 2);  // V^T [bh][d][t]
  u16* ctx = (u16*)alloc(8192ull * 1024 * 2);      // attention context bf16
  float* y1 = (float*)alloc(8192ull * 1024 * 4);   // pre-LN1 residual sum; reused as y2
  u16* X1b = (u16*)alloc(8192ull * 1024 * 2);      // LN1 out bf16
  float* X1f = (float*)alloc(8192ull * 1024 * 4);  // LN1 out fp32
  u16* hbuf = Qb;  // FF1 output (64 MB) aliases Qb..ctx (dead after out-proj)

  cast_bf16_k<<<8192, 256, 0, stream>>>(X, Xb);
  transpose_cast_k<<<dim3(96, 32), 256, 0, stream>>>(W_qkv, Wqkvt, 1024, 3072);
  transpose_cast_k<<<dim3(32, 32), 256, 0, stream>>>(W_out, Woutt, 1024, 1024);
  transpose_cast_k<<<dim3(128, 32), 256, 0, stream>>>(W_ff1, Wff1t, 1024, 4096);
  transpose_cast_k<<<dim3(32, 128), 256, 0, stream>>>(W_ff2, Wff2t, 4096, 1024);

  // QKV projection + head scatter   (grid 768 = 32m x 24n, 3 full rounds)
  gemm8n<0><<<768, 512, 0, stream>>>(Xb, Wqkvt, b_qkv, nullptr, nullptr, nullptr,
                                     Qb, Kb, Vtb, 8192, 3072, 1024);
  // flash attention
  attn_flash_k<<<dim3(16, 128), 256, 0, stream>>>(Qb, Kb, Vtb, ctx);
  // out projection + bias + residual(X) -> y1 fp32   (grid 256 = full round)
  gemm8n<1><<<256, 512, 0, stream>>>(ctx, Woutt, b_out, X, y1, nullptr,
                                     nullptr, nullptr, nullptr, 8192, 1024, 1024);
  // LN1 -> X1 (bf16 + fp32)
  layernorm_k<<<8192, 256, 0, stream>>>(y1, ln1_g, ln1_b, X1b, X1f);
  // FF1 + bias + exact GELU -> h bf16   (grid 512 = 2 full rounds, 256x256 tiles)
  gemm8<2><<<512, 512, 0, stream>>>(X1b, Wff1t, b_ff1, nullptr, nullptr, hbuf,
                                    nullptr, nullptr, nullptr, 8192, 4096, 1024);
  // FF2 + bias + residual(X1) -> y2 fp32   (grid 256 = full round)
  gemm8n<1><<<256, 512, 0, stream>>>(hbuf, Wff2t, b_ff2, X1f, y1, nullptr,
                                     nullptr, nullptr, nullptr, 8192, 1024, 4096);
  // LN2 -> output fp32
  layernorm_k<<<8192, 256, 0, stream>>>(y1, ln2_g, ln2_b, nullptr, (float*)d_out);
}